// Round 9
// baseline (329.537 us; speedup 1.0000x reference)
//
#include <hip/hip_runtime.h>
#include <math.h>

#define NN 100000
#define NE 1600000
#define CH 128
#define OUTC 16
#define NG 64

#define CBSH 8                      // 256 nodes per coarse bucket
#define NCB 391                     // ceil(NN / 256)
#define CHK 4096                    // edges per passA block  (391 blocks)
#define HCHK 8192                   // edges per hist block   (196 blocks)
#define HISTB 196
#define PREPB 391
#define MAXB 6144                   // csr staging cap per bucket (avg 4092, +32 sigma)
#define PS 8                        // pool splits per graph
#define LDA 136                     // LDS W-tile row stride in ushorts (272 B)

typedef __attribute__((ext_vector_type(8))) short bf16x8;
typedef __attribute__((ext_vector_type(4))) float f32x4;

__device__ __forceinline__ unsigned short f2bf(float f) {
    union { float f; unsigned u; } v; v.f = f;
    unsigned r = v.u + 0x7FFF + ((v.u >> 16) & 1);   // RNE
    return (unsigned short)(r >> 16);
}
__device__ __forceinline__ float bflo(unsigned u) {
    union { unsigned u; float f; } v; v.u = u << 16; return v.f;
}
__device__ __forceinline__ float bfhi(unsigned u) {
    union { unsigned u; float f; } v; v.u = u & 0xffff0000u; return v.f;
}

// ---------------- fused0: hist (global-atomic bcnt) | prep ----------------
__global__ __launch_bounds__(256) void k_fused0(const int* __restrict__ edst, int* __restrict__ bcnt,
                         const float* __restrict__ W2, unsigned short* __restrict__ wt2,
                         const int* __restrict__ batch, int* __restrict__ gptr,
                         int* __restrict__ gfill, float* __restrict__ pooled,
                         int* __restrict__ done) {
    int b = blockIdx.x;
    int t = threadIdx.x;
    if (b < HISTB) {
        __shared__ int h[NCB];
        for (int i = t; i < NCB; i += 256) h[i] = 0;
        __syncthreads();
        int base = b * HCHK;
#pragma unroll
        for (int i = 0; i < 32; i++) {
            int e = base + i * 256 + t;
            if (e < NE) atomicAdd(&h[edst[e] >> CBSH], 1);
        }
        __syncthreads();
        for (int i = t; i < NCB; i += 256)
            if (h[i]) atomicAdd(&bcnt[i], h[i]);
    } else {
        int i = (b - HISTB) * 256 + t;
        if (i < CH * CH) {
            int k = i >> 7, n = i & 127;
            wt2[n * CH + k] = f2bf(W2[i]);
        }
        if (i < NCB) gfill[i] = 0;
        if (i < NG * CH) pooled[i] = 0.f;
        if (i == 0) *done = 0;
        if (i < NN) {
            int bb = batch[i];
            int prev = (i == 0) ? -1 : batch[i - 1];
            for (int g = prev + 1; g <= bb; g++) gptr[g] = i;
            if (i == NN - 1) {
                for (int g = bb + 1; g <= NG; g++) gptr[g] = NN;
            }
        }
    }
}

// ---------------- pass A: counting-sort edges into 391 coarse buckets ----------
__global__ __launch_bounds__(512) void k_passA(const int* __restrict__ src, const int* __restrict__ dst,
                        const int* __restrict__ bcnt, int* __restrict__ gfill,
                        unsigned* __restrict__ ebuf, int* __restrict__ ebase) {
    __shared__ unsigned lbuf[CHK];
    __shared__ unsigned short lbkt[CHK];
    __shared__ int hcnt[NCB];
    __shared__ int hbase[512];   // inclusive scan of hcnt
    __shared__ int eb[512];      // inclusive scan of bcnt
    __shared__ int goff[NCB];
    int t = threadIdx.x;
    for (int i = t; i < NCB; i += 512) hcnt[i] = 0;
    eb[t] = (t < NCB) ? bcnt[t] : 0;
    __syncthreads();
    int base = blockIdx.x * CHK;
    int cb[8], slot[8]; unsigned pk[8];
#pragma unroll
    for (int i = 0; i < 8; i++) {
        int e = base + i * 512 + t;
        cb[i] = -1;
        if (e < NE) {
            int d = dst[e], s = src[e];
            cb[i] = d >> CBSH;
            pk[i] = ((unsigned)s << CBSH) | (unsigned)(d & 255);
            slot[i] = atomicAdd(&hcnt[cb[i]], 1);
        }
    }
    __syncthreads();
    hbase[t] = (t < NCB) ? hcnt[t] : 0;
    __syncthreads();
    for (int off = 1; off < 512; off <<= 1) {
        int v1 = 0, v2 = 0;
        if (t >= off) { v1 = hbase[t - off]; v2 = eb[t - off]; }
        __syncthreads();
        if (t >= off) { hbase[t] += v1; eb[t] += v2; }
        __syncthreads();
    }
    if (t < NCB) {
        int c = hcnt[t];
        int g = c ? atomicAdd(&gfill[t], c) : 0;
        int eb_ex = t ? eb[t - 1] : 0;
        goff[t] = eb_ex + g - (hbase[t] - c);
    }
    if (blockIdx.x == 0) {
        if (t == 0) ebase[0] = 0;
        if (t < NCB) ebase[t + 1] = eb[t];
    }
    __syncthreads();
#pragma unroll
    for (int i = 0; i < 8; i++) {
        if (cb[i] >= 0) {
            int pos = hbase[cb[i]] - hcnt[cb[i]] + slot[i];
            lbuf[pos] = pk[i];
            lbkt[pos] = (unsigned short)cb[i];
        }
    }
    __syncthreads();
    int total = min(NE - base, CHK);
    for (int p = t; p < total; p += 512) {
        unsigned v = lbuf[p];
        int bk = lbkt[p];
        ebuf[goff[bk] + p] = v;
    }
}

// ---------------- fusedB: passB (391 blocks) | gemm1 (782 blocks) ----------------
// gemm1: bf16(x @ W1) UNSCALED, operand-SWAPPED mfma (R4-verified): D col=node,
// row=4 contiguous channels per lane -> uint2 stores (16/lane, not 64 scalar).
__launch_bounds__(256, 2)
__global__ void k_fusedB(const unsigned* __restrict__ ebuf, const int* __restrict__ ebase,
                         int* __restrict__ degi, int* __restrict__ rowst,
                         float* __restrict__ dis, int* __restrict__ csr,
                         const float* __restrict__ x, const float* __restrict__ W1,
                         unsigned short* __restrict__ bufA) {
    __shared__ __align__(16) unsigned short smem[128 * LDA];   // 34816 B
    int b = blockIdx.x;
    int t = threadIdx.x;

    if (b < NCB) {
        // ---- passB ----
        int* cnt   = (int*)smem;
        int* nbase = cnt + 256;
        int* fill  = nbase + 256;
        int* stage = fill + 256;
        int cb = b;
        int nb0 = cb << CBSH;
        int ncnt = min(256, NN - nb0);
        int e0 = ebase[cb], e1 = ebase[cb + 1];
        cnt[t] = 0; fill[t] = 0;
        __syncthreads();
        for (int e = e0 + t; e < e1; e += 256)
            atomicAdd(&cnt[ebuf[e] & 255], 1);
        __syncthreads();
        nbase[t] = cnt[t];
        __syncthreads();
        for (int off = 1; off < 256; off <<= 1) {
            int v = 0;
            if (t >= off) v = nbase[t - off];
            __syncthreads();
            if (t >= off) nbase[t] += v;
            __syncthreads();
        }
        for (int e = e0 + t; e < e1; e += 256) {
            unsigned v = ebuf[e];
            int local = v & 255;
            int s = atomicAdd(&fill[local], 1);
            stage[nbase[local] - cnt[local] + s] = (int)(v >> CBSH);
        }
        __syncthreads();
        int total = e1 - e0;
        for (int p = t; p < total; p += 256) csr[e0 + p] = stage[p];
        if (t < ncnt) {
            int c = cnt[t];
            degi[nb0 + t] = c;
            rowst[nb0 + t] = e0 + nbase[t] - c;
            dis[nb0 + t] = rsqrtf((float)c + 1.0f);
        }
    } else {
        // ---- gemm1 ----
        unsigned short* wlds = smem;
#pragma unroll
        for (int it = 0; it < 64; it++) {
            int i = it * 256 + t;                 // i = k*128 + n
            int k = i >> 7, n = i & 127;
            wlds[n * LDA + k] = f2bf(W1[i]);
        }
        __syncthreads();

        int wave = t >> 6, lane = t & 63;
        int quad = lane >> 4, l16 = lane & 15;
        int rbase = (b - NCB) * 128 + wave * 32;

        bf16x8 af[2][4];
#pragma unroll
        for (int s = 0; s < 2; s++) {
            int row = rbase + s * 16 + l16;
            if (row >= NN) row = NN - 1;
            const float* arow = x + (size_t)row * CH + quad * 8;
#pragma unroll
            for (int ks = 0; ks < 4; ks++) {
                float4 lo = *(const float4*)(arow + ks * 32);
                float4 hi = *(const float4*)(arow + ks * 32 + 4);
                union { bf16x8 v; unsigned short u[8]; } tmp;
                tmp.u[0] = f2bf(lo.x); tmp.u[1] = f2bf(lo.y);
                tmp.u[2] = f2bf(lo.z); tmp.u[3] = f2bf(lo.w);
                tmp.u[4] = f2bf(hi.x); tmp.u[5] = f2bf(hi.y);
                tmp.u[6] = f2bf(hi.z); tmp.u[7] = f2bf(hi.w);
                af[s][ks] = tmp.v;
            }
        }

        f32x4 acc[2][8];
#pragma unroll
        for (int s = 0; s < 2; s++)
#pragma unroll
            for (int tt = 0; tt < 8; tt++) acc[s][tt] = (f32x4){0.f, 0.f, 0.f, 0.f};

#pragma unroll
        for (int tt = 0; tt < 8; tt++) {
            const unsigned short* wcol = &wlds[(tt * 16 + l16) * LDA + quad * 8];
            bf16x8 b0 = *(const bf16x8*)(wcol);
            bf16x8 b1 = *(const bf16x8*)(wcol + 32);
            bf16x8 b2 = *(const bf16x8*)(wcol + 64);
            bf16x8 b3 = *(const bf16x8*)(wcol + 96);
#pragma unroll
            for (int s = 0; s < 2; s++) {
                acc[s][tt] = __builtin_amdgcn_mfma_f32_16x16x32_bf16(b0, af[s][0], acc[s][tt], 0, 0, 0);
                acc[s][tt] = __builtin_amdgcn_mfma_f32_16x16x32_bf16(b1, af[s][1], acc[s][tt], 0, 0, 0);
                acc[s][tt] = __builtin_amdgcn_mfma_f32_16x16x32_bf16(b2, af[s][2], acc[s][tt], 0, 0, 0);
                acc[s][tt] = __builtin_amdgcn_mfma_f32_16x16x32_bf16(b3, af[s][3], acc[s][tt], 0, 0, 0);
            }
        }

        // Swapped D layout: node = rbase + s*16 + l16, channel = tt*16 + quad*4 + r
#pragma unroll
        for (int s = 0; s < 2; s++) {
            int node = rbase + s * 16 + l16;
            if (node < NN) {
#pragma unroll
                for (int tt = 0; tt < 8; tt++) {
                    unsigned lo = ((unsigned)f2bf(acc[s][tt][1]) << 16) | (unsigned)f2bf(acc[s][tt][0]);
                    unsigned hi = ((unsigned)f2bf(acc[s][tt][3]) << 16) | (unsigned)f2bf(acc[s][tt][2]);
                    uint2 pk; pk.x = lo; pk.y = hi;
                    *(uint2*)(bufA + (size_t)node * CH + tt * 16 + quad * 4) = pk;
                }
            }
        }
    }
}

// ---------------- agg layer 1 (dis-WEIGHTED gather) — proven, verbatim ----------
__global__ __launch_bounds__(256) void k_agg_w(const unsigned short* __restrict__ ht, const int* __restrict__ rowst,
                      const int* __restrict__ degi, const int* __restrict__ csr,
                      const float* __restrict__ dis, const float* __restrict__ bias,
                      unsigned short* __restrict__ out) {
    int t = threadIdx.x;
    int grp = t >> 4;
    int q = t & 15;
    int n = blockIdx.x * 16 + grp;   // NN = 6250*16 exactly
    const uint4* base = (const uint4*)ht;

    float d = dis[n];
    uint4 sv = base[(size_t)n * 16 + q];
    float a[8];
    a[0] = d * bflo(sv.x); a[1] = d * bfhi(sv.x);
    a[2] = d * bflo(sv.y); a[3] = d * bfhi(sv.y);
    a[4] = d * bflo(sv.z); a[5] = d * bfhi(sv.z);
    a[6] = d * bflo(sv.w); a[7] = d * bfhi(sv.w);

    int start = rowst[n];
    int c = degi[n];
    int nb = c & ~7;
    int j = 0;
    for (; j < nb; j += 8) {
        int idx[8];
#pragma unroll
        for (int u = 0; u < 8; u++) idx[u] = csr[start + j + u];
        uint4 v[8]; float w[8];
#pragma unroll
        for (int u = 0; u < 8; u++) v[u] = base[(size_t)idx[u] * 16 + q];
#pragma unroll
        for (int u = 0; u < 8; u++) w[u] = dis[idx[u]];
#pragma unroll
        for (int u = 0; u < 8; u++) {
            a[0] = fmaf(w[u], bflo(v[u].x), a[0]); a[1] = fmaf(w[u], bfhi(v[u].x), a[1]);
            a[2] = fmaf(w[u], bflo(v[u].y), a[2]); a[3] = fmaf(w[u], bfhi(v[u].y), a[3]);
            a[4] = fmaf(w[u], bflo(v[u].z), a[4]); a[5] = fmaf(w[u], bfhi(v[u].z), a[5]);
            a[6] = fmaf(w[u], bflo(v[u].w), a[6]); a[7] = fmaf(w[u], bfhi(v[u].w), a[7]);
        }
    }
    if (j < c) {
        int idx[8];
#pragma unroll
        for (int u = 0; u < 8; u++) { int e = j + u; idx[u] = csr[start + (e < c ? e : c - 1)]; }
        uint4 v[8]; float w[8];
#pragma unroll
        for (int u = 0; u < 8; u++) v[u] = base[(size_t)idx[u] * 16 + q];
#pragma unroll
        for (int u = 0; u < 8; u++) w[u] = dis[idx[u]];
#pragma unroll
        for (int u = 0; u < 8; u++) {
            if (j + u < c) {
                a[0] = fmaf(w[u], bflo(v[u].x), a[0]); a[1] = fmaf(w[u], bfhi(v[u].x), a[1]);
                a[2] = fmaf(w[u], bflo(v[u].y), a[2]); a[3] = fmaf(w[u], bfhi(v[u].y), a[3]);
                a[4] = fmaf(w[u], bflo(v[u].z), a[4]); a[5] = fmaf(w[u], bfhi(v[u].z), a[5]);
                a[6] = fmaf(w[u], bflo(v[u].w), a[6]); a[7] = fmaf(w[u], bfhi(v[u].w), a[7]);
            }
        }
    }

    const float4* bp = (const float4*)bias;
    float4 b0 = bp[q * 2], b1 = bp[q * 2 + 1];
    uint4 o;
    {
        float ox = fmaxf(fmaf(d, a[0], b0.x), 0.f), oy = fmaxf(fmaf(d, a[1], b0.y), 0.f);
        o.x = ((unsigned)f2bf(oy) << 16) | (unsigned)f2bf(ox);
        ox = fmaxf(fmaf(d, a[2], b0.z), 0.f); oy = fmaxf(fmaf(d, a[3], b0.w), 0.f);
        o.y = ((unsigned)f2bf(oy) << 16) | (unsigned)f2bf(ox);
        ox = fmaxf(fmaf(d, a[4], b1.x), 0.f); oy = fmaxf(fmaf(d, a[5], b1.y), 0.f);
        o.z = ((unsigned)f2bf(oy) << 16) | (unsigned)f2bf(ox);
        ox = fmaxf(fmaf(d, a[6], b1.z), 0.f); oy = fmaxf(fmaf(d, a[7], b1.w), 0.f);
        o.w = ((unsigned)f2bf(oy) << 16) | (unsigned)f2bf(ox);
    }
    ((uint4*)out)[(size_t)n * 16 + q] = o;
}

// ---------------- MFMA GEMM layer 2: swapped mfma + uint2 stores (R4-verified) ----
__launch_bounds__(256, 2)
__global__ void k_gemm2(const unsigned short* __restrict__ Av,
                        const unsigned short* __restrict__ WT,
                        const float* __restrict__ dis,
                        unsigned short* __restrict__ out) {
    int tid = threadIdx.x;
    int wave = tid >> 6, lane = tid & 63;
    int quad = lane >> 4, l16 = lane & 15;

    int rbase = blockIdx.x * 128 + wave * 32;

    bf16x8 af[2][4];
#pragma unroll
    for (int s = 0; s < 2; s++) {
        int row = rbase + s * 16 + l16;
        if (row >= NN) row = NN - 1;
        const unsigned short* arow = Av + (size_t)row * CH + quad * 8;
#pragma unroll
        for (int ks = 0; ks < 4; ks++) af[s][ks] = *(const bf16x8*)(arow + ks * 32);
    }

    f32x4 acc[2][8];
#pragma unroll
    for (int s = 0; s < 2; s++)
#pragma unroll
        for (int t = 0; t < 8; t++) acc[s][t] = (f32x4){0.f, 0.f, 0.f, 0.f};

#pragma unroll
    for (int t = 0; t < 8; t++) {
        const unsigned short* wcol = WT + (size_t)(t * 16 + l16) * CH + quad * 8;
        bf16x8 b0 = *(const bf16x8*)(wcol);
        bf16x8 b1 = *(const bf16x8*)(wcol + 32);
        bf16x8 b2 = *(const bf16x8*)(wcol + 64);
        bf16x8 b3 = *(const bf16x8*)(wcol + 96);
#pragma unroll
        for (int s = 0; s < 2; s++) {
            acc[s][t] = __builtin_amdgcn_mfma_f32_16x16x32_bf16(b0, af[s][0], acc[s][t], 0, 0, 0);
            acc[s][t] = __builtin_amdgcn_mfma_f32_16x16x32_bf16(b1, af[s][1], acc[s][t], 0, 0, 0);
            acc[s][t] = __builtin_amdgcn_mfma_f32_16x16x32_bf16(b2, af[s][2], acc[s][t], 0, 0, 0);
            acc[s][t] = __builtin_amdgcn_mfma_f32_16x16x32_bf16(b3, af[s][3], acc[s][t], 0, 0, 0);
        }
    }

    // Swapped D layout: node = rbase + s*16 + l16, channel = t*16 + quad*4 + r
#pragma unroll
    for (int s = 0; s < 2; s++) {
        int node = rbase + s * 16 + l16;
        int cl = (node < NN) ? node : NN - 1;
        float d = dis[cl];
        if (node < NN) {
#pragma unroll
            for (int t = 0; t < 8; t++) {
                unsigned lo = ((unsigned)f2bf(acc[s][t][1] * d) << 16) | (unsigned)f2bf(acc[s][t][0] * d);
                unsigned hi = ((unsigned)f2bf(acc[s][t][3] * d) << 16) | (unsigned)f2bf(acc[s][t][2] * d);
                uint2 pk; pk.x = lo; pk.y = hi;
                *(uint2*)(out + (size_t)node * CH + t * 16 + quad * 4) = pk;
            }
        }
    }
}

// ---------------- agg layer 2: proven kernel, verbatim (59.7 us floor) ----------
__global__ __launch_bounds__(256) void k_agg(const unsigned short* __restrict__ ht, const int* __restrict__ rowst,
                      const int* __restrict__ degi, const int* __restrict__ csr,
                      const float* __restrict__ dis, const float* __restrict__ bias,
                      unsigned short* __restrict__ out) {
    int t = threadIdx.x;
    int grp = t >> 4;
    int q = t & 15;
    int n = blockIdx.x * 16 + grp;
    const uint4* base = (const uint4*)ht;

    uint4 sv = base[(size_t)n * 16 + q];
    float a[8];
    a[0] = bflo(sv.x); a[1] = bfhi(sv.x);
    a[2] = bflo(sv.y); a[3] = bfhi(sv.y);
    a[4] = bflo(sv.z); a[5] = bfhi(sv.z);
    a[6] = bflo(sv.w); a[7] = bfhi(sv.w);

    int start = rowst[n];
    int c = degi[n];
    int nb = c & ~7;
    int j = 0;
    for (; j < nb; j += 8) {
        int idx[8];
#pragma unroll
        for (int u = 0; u < 8; u++) idx[u] = csr[start + j + u];
        uint4 v[8];
#pragma unroll
        for (int u = 0; u < 8; u++) v[u] = base[(size_t)idx[u] * 16 + q];
#pragma unroll
        for (int u = 0; u < 8; u++) {
            a[0] += bflo(v[u].x); a[1] += bfhi(v[u].x);
            a[2] += bflo(v[u].y); a[3] += bfhi(v[u].y);
            a[4] += bflo(v[u].z); a[5] += bfhi(v[u].z);
            a[6] += bflo(v[u].w); a[7] += bfhi(v[u].w);
        }
    }
    if (j < c) {
        int idx[8];
#pragma unroll
        for (int u = 0; u < 8; u++) { int e = j + u; idx[u] = csr[start + (e < c ? e : c - 1)]; }
        uint4 v[8];
#pragma unroll
        for (int u = 0; u < 8; u++) v[u] = base[(size_t)idx[u] * 16 + q];
#pragma unroll
        for (int u = 0; u < 8; u++) {
            if (j + u < c) {
                a[0] += bflo(v[u].x); a[1] += bfhi(v[u].x);
                a[2] += bflo(v[u].y); a[3] += bfhi(v[u].y);
                a[4] += bflo(v[u].z); a[5] += bfhi(v[u].z);
                a[6] += bflo(v[u].w); a[7] += bfhi(v[u].w);
            }
        }
    }

    float d = dis[n];
    const float4* bp = (const float4*)bias;
    float4 b0 = bp[q * 2], b1 = bp[q * 2 + 1];
    uint4 o;
    {
        float ox = fmaxf(fmaf(d, a[0], b0.x), 0.f), oy = fmaxf(fmaf(d, a[1], b0.y), 0.f);
        o.x = ((unsigned)f2bf(oy) << 16) | (unsigned)f2bf(ox);
        ox = fmaxf(fmaf(d, a[2], b0.z), 0.f); oy = fmaxf(fmaf(d, a[3], b0.w), 0.f);
        o.y = ((unsigned)f2bf(oy) << 16) | (unsigned)f2bf(ox);
        ox = fmaxf(fmaf(d, a[4], b1.x), 0.f); oy = fmaxf(fmaf(d, a[5], b1.y), 0.f);
        o.z = ((unsigned)f2bf(oy) << 16) | (unsigned)f2bf(ox);
        ox = fmaxf(fmaf(d, a[6], b1.z), 0.f); oy = fmaxf(fmaf(d, a[7], b1.w), 0.f);
        o.w = ((unsigned)f2bf(oy) << 16) | (unsigned)f2bf(ox);
    }
    ((uint4*)out)[(size_t)n * 16 + q] = o;
}

// ---------------- mean pool + final FC (fused, last-block ticket; R4-verified) ----
__global__ __launch_bounds__(512) void k_pool_final(const unsigned short* __restrict__ h,
                                               const int* __restrict__ gptr,
                                               float* __restrict__ pooled,
                                               int* __restrict__ done,
                                               const float* __restrict__ Wfc,
                                               const float* __restrict__ bfc,
                                               float* __restrict__ out) {
    int g = blockIdx.x >> 3;       // graph
    int s = blockIdx.x & 7;        // split
    int gs = gptr[g], ge = gptr[g + 1];
    int len = ge - gs;
    int i0 = gs + (int)(((long long)len * s) >> 3);
    int i1 = gs + (int)(((long long)len * (s + 1)) >> 3);
    int t = threadIdx.x;
    int pr = t & 63;               // channel pair 0..63
    int ro = t >> 6;               // row group 0..7
    const unsigned* base = (const unsigned*)h;
    float s0 = 0.f, s1 = 0.f;
    for (int n = i0 + ro; n < i1; n += 8) {
        unsigned v = base[(size_t)n * 64 + pr];
        s0 += bflo(v); s1 += bfhi(v);
    }
    __shared__ float red[2][8][64];
    red[0][ro][pr] = s0; red[1][ro][pr] = s1;
    __syncthreads();
    for (int off = 4; off >= 1; off >>= 1) {
        if (ro < off) {
            red[0][ro][pr] += red[0][ro + off][pr];
            red[1][ro][pr] += red[1][ro + off][pr];
        }
        __syncthreads();
    }
    if (ro == 0) {
        atomicAdd(&pooled[g * CH + pr * 2],     red[0][0][pr]);
        atomicAdd(&pooled[g * CH + pr * 2 + 1], red[1][0][pr]);
    }

    // ---- ticket: last block computes the FC head ----
    __shared__ int lastFlag;
    __shared__ float plds[NG * CH];
    __syncthreads();
    if (t == 0) {
        __threadfence();
        int r = atomicAdd(done, 1);
        lastFlag = (r == NG * PS - 1) ? 1 : 0;
    }
    __syncthreads();
    if (!lastFlag) return;
    for (int i = t; i < NG * CH; i += 512) plds[i] = atomicAdd(&pooled[i], 0.0f);
    __syncthreads();
    for (int idx = t; idx < NG * OUTC; idx += 512) {
        int gg = idx >> 4, o = idx & 15;
        float c = (float)(gptr[gg + 1] - gptr[gg]);
        float inv = 1.0f / fmaxf(c, 1.0f);
        float acc = 0.f;
        for (int k = 0; k < CH; k++) acc += plds[gg * CH + k] * Wfc[k * OUTC + o];
        out[idx] = fmaf(acc, inv, bfc[o]);
    }
}

extern "C" void kernel_launch(void* const* d_in, const int* in_sizes, int n_in,
                              void* d_out, int out_size, void* d_ws, size_t ws_size,
                              hipStream_t stream) {
    (void)in_sizes; (void)n_in; (void)out_size; (void)ws_size;
    const float* x   = (const float*)d_in[0];
    const float* W1  = (const float*)d_in[1];
    const float* b1  = (const float*)d_in[2];
    const float* W2  = (const float*)d_in[3];
    const float* b2  = (const float*)d_in[4];
    const float* Wfc = (const float*)d_in[5];
    const float* bfc = (const float*)d_in[6];
    const int* ei    = (const int*)d_in[7];
    const int* batch = (const int*)d_in[8];
    const int* esrc = ei;
    const int* edst = ei + NE;
    float* out = (float*)d_out;

    char* w = (char*)d_ws;
    unsigned short* bufA = (unsigned short*)w; w += (size_t)NN * CH * 2;
    unsigned short* bufB = (unsigned short*)w; w += (size_t)NN * CH * 2;
    unsigned short* wt2  = (unsigned short*)w; w += (size_t)CH * CH * 2;
    unsigned* ebuf = (unsigned*)w; w += (size_t)NE * 4;
    int* csr    = (int*)w;    w += (size_t)NE * 4;
    int* degi   = (int*)w;    w += (size_t)NN * 4;
    int* rowst  = (int*)w;    w += (size_t)NN * 4;
    float* dis  = (float*)w;  w += (size_t)NN * 4;
    int* bcnt   = (int*)w;    w += NCB * 4;
    int* ebase  = (int*)w;    w += (NCB + 1) * 4;
    int* gfill  = (int*)w;    w += NCB * 4;
    int* gptr   = (int*)w;    w += (NG + 1) * 4;
    float* pooled = (float*)w; w += (size_t)NG * CH * 4;
    int* done   = (int*)w;    w += 4;

    const int gemmBlocks = (NN + 127) / 128;         // 782
    const int aggBlocks  = NN / 16;                  // 6250
    const int passABlocks = (NE + CHK - 1) / CHK;    // 391

    hipMemsetAsync(bcnt, 0, NCB * sizeof(int), stream);

    // fused: hist (global-atomic bcnt) | prep
    k_fused0<<<HISTB + PREPB, 256, 0, stream>>>(edst, bcnt, W2, wt2, batch, gptr, gfill, pooled, done);
    // counting-sort pass A (391 blocks, folded bucket-base scan; block 0 -> ebase)
    k_passA<<<passABlocks, 512, 0, stream>>>(esrc, edst, bcnt, gfill, ebuf, ebase);
    // fused: passB (391 blocks) | gemm1 (782 blocks, unscaled, swapped epilogue)
    k_fusedB<<<NCB + gemmBlocks, 256, 0, stream>>>(ebuf, ebase, degi, rowst, dis, csr, x, W1, bufA);

    // layer 1 aggregation (dis-weighted gather over unscaled bufA)
    k_agg_w<<<aggBlocks, 256, 0, stream>>>(bufA, rowst, degi, csr, dis, b1, bufB);
    // layer 2 (bf16 input, dis-scaled output, swapped epilogue)
    k_gemm2<<<gemmBlocks, 256, 0, stream>>>(bufB, wt2, dis, bufA);
    k_agg<<<aggBlocks, 256, 0, stream>>>(bufA, rowst, degi, csr, dis, b2, bufB);

    // fused: mean pool + FC head
    k_pool_final<<<NG * PS, 512, 0, stream>>>(bufB, gptr, pooled, done, Wfc, bfc, out);
}

// Round 11
// 313.507 us; speedup vs baseline: 1.0511x; 1.0511x over previous
//
#include <hip/hip_runtime.h>
#include <math.h>

#define NN 100000
#define NE 1600000
#define CH 128
#define OUTC 16
#define NG 64

#define CBSH 8                      // 256 nodes per coarse bucket
#define NCB 391                     // ceil(NN / 256)
#define CHK 4096                    // edges per passA block  (391 blocks)
#define HCHK 8192                   // edges per hist block   (196 blocks)
#define HISTB 196
#define PREPB 391
#define MAXB 6144                   // csr staging cap per bucket (avg 4092, +32 sigma)
#define PS 8                        // pool splits per graph
#define LDA 136                     // LDS W-tile row stride in ushorts (272 B)

typedef __attribute__((ext_vector_type(8))) short bf16x8;
typedef __attribute__((ext_vector_type(4))) float f32x4;

__device__ __forceinline__ unsigned short f2bf(float f) {
    union { float f; unsigned u; } v; v.f = f;
    unsigned r = v.u + 0x7FFF + ((v.u >> 16) & 1);   // RNE
    return (unsigned short)(r >> 16);
}
__device__ __forceinline__ float bflo(unsigned u) {
    union { unsigned u; float f; } v; v.u = u << 16; return v.f;
}
__device__ __forceinline__ float bfhi(unsigned u) {
    union { unsigned u; float f; } v; v.u = u & 0xffff0000u; return v.f;
}

// ---------------- fused0: hist (global-atomic bcnt) | prep ----------------
// bcnt pre-zeroed by hipMemsetAsync; hist blocks accumulate per-block LDS
// histograms then flush atomically (R1-proven). prep casts W2, builds gptr,
// zeroes gfill/pooled. Branches disjoint, no shared data.
__global__ __launch_bounds__(256) void k_fused0(const int* __restrict__ edst, int* __restrict__ bcnt,
                         const float* __restrict__ W2, unsigned short* __restrict__ wt2,
                         const int* __restrict__ batch, int* __restrict__ gptr,
                         int* __restrict__ gfill, float* __restrict__ pooled) {
    int b = blockIdx.x;
    int t = threadIdx.x;
    if (b < HISTB) {
        __shared__ int h[NCB];
        for (int i = t; i < NCB; i += 256) h[i] = 0;
        __syncthreads();
        int base = b * HCHK;
#pragma unroll
        for (int i = 0; i < 32; i++) {
            int e = base + i * 256 + t;
            if (e < NE) atomicAdd(&h[edst[e] >> CBSH], 1);
        }
        __syncthreads();
        for (int i = t; i < NCB; i += 256)
            if (h[i]) atomicAdd(&bcnt[i], h[i]);
    } else {
        int i = (b - HISTB) * 256 + t;
        if (i < CH * CH) {
            int k = i >> 7, n = i & 127;
            wt2[n * CH + k] = f2bf(W2[i]);
        }
        if (i < NCB) gfill[i] = 0;
        if (i < NG * CH) pooled[i] = 0.f;
        if (i < NN) {
            int bb = batch[i];
            int prev = (i == 0) ? -1 : batch[i - 1];
            for (int g = prev + 1; g <= bb; g++) gptr[g] = i;
            if (i == NN - 1) {
                for (int g = bb + 1; g <= NG; g++) gptr[g] = NN;
            }
        }
    }
}

// ---------------- pass A: counting-sort edges into 391 coarse buckets ----------
// 512 threads, 4096 edges/block. Bucket-base scan folded in-block (eb[] rides
// the hbase scan rounds); block 0 publishes ebase for passB.
__global__ __launch_bounds__(512) void k_passA(const int* __restrict__ src, const int* __restrict__ dst,
                        const int* __restrict__ bcnt, int* __restrict__ gfill,
                        unsigned* __restrict__ ebuf, int* __restrict__ ebase) {
    __shared__ unsigned lbuf[CHK];
    __shared__ unsigned short lbkt[CHK];
    __shared__ int hcnt[NCB];
    __shared__ int hbase[512];   // inclusive scan of hcnt
    __shared__ int eb[512];      // inclusive scan of bcnt
    __shared__ int goff[NCB];
    int t = threadIdx.x;
    for (int i = t; i < NCB; i += 512) hcnt[i] = 0;
    eb[t] = (t < NCB) ? bcnt[t] : 0;
    __syncthreads();
    int base = blockIdx.x * CHK;
    int cb[8], slot[8]; unsigned pk[8];
#pragma unroll
    for (int i = 0; i < 8; i++) {
        int e = base + i * 512 + t;
        cb[i] = -1;
        if (e < NE) {
            int d = dst[e], s = src[e];
            cb[i] = d >> CBSH;
            pk[i] = ((unsigned)s << CBSH) | (unsigned)(d & 255);
            slot[i] = atomicAdd(&hcnt[cb[i]], 1);
        }
    }
    __syncthreads();
    hbase[t] = (t < NCB) ? hcnt[t] : 0;
    __syncthreads();
    for (int off = 1; off < 512; off <<= 1) {
        int v1 = 0, v2 = 0;
        if (t >= off) { v1 = hbase[t - off]; v2 = eb[t - off]; }
        __syncthreads();
        if (t >= off) { hbase[t] += v1; eb[t] += v2; }
        __syncthreads();
    }
    if (t < NCB) {
        int c = hcnt[t];
        int g = c ? atomicAdd(&gfill[t], c) : 0;
        int eb_ex = t ? eb[t - 1] : 0;
        goff[t] = eb_ex + g - (hbase[t] - c);
    }
    if (blockIdx.x == 0) {
        if (t == 0) ebase[0] = 0;
        if (t < NCB) ebase[t + 1] = eb[t];
    }
    __syncthreads();
#pragma unroll
    for (int i = 0; i < 8; i++) {
        if (cb[i] >= 0) {
            int pos = hbase[cb[i]] - hcnt[cb[i]] + slot[i];
            lbuf[pos] = pk[i];
            lbkt[pos] = (unsigned short)cb[i];
        }
    }
    __syncthreads();
    int total = min(NE - base, CHK);
    for (int p = t; p < total; p += 512) {
        unsigned v = lbuf[p];
        int bk = lbkt[p];
        ebuf[goff[bk] + p] = v;
    }
}

// ---------------- fusedB: passB (391 blocks) | gemm1 (782 blocks) ----------------
// passB: per-bucket (256 nodes) sort -> csr/degi/rowst/dis, reads ebase.
// gemm1: bf16((x @ W1)) UNSCALED (agg_w applies dis weights), self-staged W1^T.
// Disjoint branches share one 34.8 KB LDS buffer.
__launch_bounds__(256, 2)
__global__ void k_fusedB(const unsigned* __restrict__ ebuf, const int* __restrict__ ebase,
                         int* __restrict__ degi, int* __restrict__ rowst,
                         float* __restrict__ dis, int* __restrict__ csr,
                         const float* __restrict__ x, const float* __restrict__ W1,
                         unsigned short* __restrict__ bufA) {
    __shared__ __align__(16) unsigned short smem[128 * LDA];   // 34816 B
    int b = blockIdx.x;
    int t = threadIdx.x;

    if (b < NCB) {
        // ---- passB ----
        int* cnt   = (int*)smem;
        int* nbase = cnt + 256;
        int* fill  = nbase + 256;
        int* stage = fill + 256;          // MAXB ints => total 27.6 KB
        int cb = b;
        int nb0 = cb << CBSH;
        int ncnt = min(256, NN - nb0);
        int e0 = ebase[cb], e1 = ebase[cb + 1];
        cnt[t] = 0; fill[t] = 0;
        __syncthreads();
        for (int e = e0 + t; e < e1; e += 256)
            atomicAdd(&cnt[ebuf[e] & 255], 1);
        __syncthreads();
        nbase[t] = cnt[t];
        __syncthreads();
        for (int off = 1; off < 256; off <<= 1) {
            int v = 0;
            if (t >= off) v = nbase[t - off];
            __syncthreads();
            if (t >= off) nbase[t] += v;
            __syncthreads();
        }
        for (int e = e0 + t; e < e1; e += 256) {
            unsigned v = ebuf[e];
            int local = v & 255;
            int s = atomicAdd(&fill[local], 1);
            stage[nbase[local] - cnt[local] + s] = (int)(v >> CBSH);
        }
        __syncthreads();
        int total = e1 - e0;
        for (int p = t; p < total; p += 256) csr[e0 + p] = stage[p];
        if (t < ncnt) {
            int c = cnt[t];
            degi[nb0 + t] = c;
            rowst[nb0 + t] = e0 + nbase[t] - c;
            dis[nb0 + t] = rsqrtf((float)c + 1.0f);
        }
    } else {
        // ---- gemm1 ----
        unsigned short* wlds = smem;
#pragma unroll
        for (int it = 0; it < 64; it++) {
            int i = it * 256 + t;                 // i = k*128 + n
            int k = i >> 7, n = i & 127;
            wlds[n * LDA + k] = f2bf(W1[i]);
        }
        __syncthreads();

        int wave = t >> 6, lane = t & 63;
        int quad = lane >> 4, l16 = lane & 15;
        int rbase = (b - NCB) * 128 + wave * 32;

        bf16x8 af[2][4];
#pragma unroll
        for (int s = 0; s < 2; s++) {
            int row = rbase + s * 16 + l16;
            if (row >= NN) row = NN - 1;
            const float* arow = x + (size_t)row * CH + quad * 8;
#pragma unroll
            for (int ks = 0; ks < 4; ks++) {
                float4 lo = *(const float4*)(arow + ks * 32);
                float4 hi = *(const float4*)(arow + ks * 32 + 4);
                union { bf16x8 v; unsigned short u[8]; } tmp;
                tmp.u[0] = f2bf(lo.x); tmp.u[1] = f2bf(lo.y);
                tmp.u[2] = f2bf(lo.z); tmp.u[3] = f2bf(lo.w);
                tmp.u[4] = f2bf(hi.x); tmp.u[5] = f2bf(hi.y);
                tmp.u[6] = f2bf(hi.z); tmp.u[7] = f2bf(hi.w);
                af[s][ks] = tmp.v;
            }
        }

        f32x4 acc[2][8];
#pragma unroll
        for (int s = 0; s < 2; s++)
#pragma unroll
            for (int tt = 0; tt < 8; tt++) acc[s][tt] = (f32x4){0.f, 0.f, 0.f, 0.f};

#pragma unroll
        for (int tt = 0; tt < 8; tt++) {
            const unsigned short* wcol = &wlds[(tt * 16 + l16) * LDA + quad * 8];
            bf16x8 b0 = *(const bf16x8*)(wcol);
            bf16x8 b1 = *(const bf16x8*)(wcol + 32);
            bf16x8 b2 = *(const bf16x8*)(wcol + 64);
            bf16x8 b3 = *(const bf16x8*)(wcol + 96);
#pragma unroll
            for (int s = 0; s < 2; s++) {
                acc[s][tt] = __builtin_amdgcn_mfma_f32_16x16x32_bf16(af[s][0], b0, acc[s][tt], 0, 0, 0);
                acc[s][tt] = __builtin_amdgcn_mfma_f32_16x16x32_bf16(af[s][1], b1, acc[s][tt], 0, 0, 0);
                acc[s][tt] = __builtin_amdgcn_mfma_f32_16x16x32_bf16(af[s][2], b2, acc[s][tt], 0, 0, 0);
                acc[s][tt] = __builtin_amdgcn_mfma_f32_16x16x32_bf16(af[s][3], b3, acc[s][tt], 0, 0, 0);
            }
        }

        // D layout per 16x16 tile: row = quad*4 + r, col = l16
#pragma unroll
        for (int s = 0; s < 2; s++) {
#pragma unroll
            for (int r = 0; r < 4; r++) {
                int orow = rbase + s * 16 + quad * 4 + r;
                if (orow < NN) {
#pragma unroll
                    for (int tt = 0; tt < 8; tt++)
                        bufA[(size_t)orow * CH + tt * 16 + l16] = f2bf(acc[s][tt][r]);
                }
            }
        }
    }
}

// ---------------- agg layer 1 (dis-WEIGHTED gather over unscaled table) ----------
// Proven R7 kernel, verbatim (62.3 us).
__global__ __launch_bounds__(256) void k_agg_w(const unsigned short* __restrict__ ht, const int* __restrict__ rowst,
                      const int* __restrict__ degi, const int* __restrict__ csr,
                      const float* __restrict__ dis, const float* __restrict__ bias,
                      unsigned short* __restrict__ out) {
    int t = threadIdx.x;
    int grp = t >> 4;
    int q = t & 15;
    int n = blockIdx.x * 16 + grp;   // NN = 6250*16 exactly
    const uint4* base = (const uint4*)ht;

    float d = dis[n];
    uint4 sv = base[(size_t)n * 16 + q];
    float a[8];
    a[0] = d * bflo(sv.x); a[1] = d * bfhi(sv.x);
    a[2] = d * bflo(sv.y); a[3] = d * bfhi(sv.y);
    a[4] = d * bflo(sv.z); a[5] = d * bfhi(sv.z);
    a[6] = d * bflo(sv.w); a[7] = d * bfhi(sv.w);

    int start = rowst[n];
    int c = degi[n];
    int nb = c & ~7;
    int j = 0;
    for (; j < nb; j += 8) {
        int idx[8];
#pragma unroll
        for (int u = 0; u < 8; u++) idx[u] = csr[start + j + u];
        uint4 v[8]; float w[8];
#pragma unroll
        for (int u = 0; u < 8; u++) v[u] = base[(size_t)idx[u] * 16 + q];
#pragma unroll
        for (int u = 0; u < 8; u++) w[u] = dis[idx[u]];
#pragma unroll
        for (int u = 0; u < 8; u++) {
            a[0] = fmaf(w[u], bflo(v[u].x), a[0]); a[1] = fmaf(w[u], bfhi(v[u].x), a[1]);
            a[2] = fmaf(w[u], bflo(v[u].y), a[2]); a[3] = fmaf(w[u], bfhi(v[u].y), a[3]);
            a[4] = fmaf(w[u], bflo(v[u].z), a[4]); a[5] = fmaf(w[u], bfhi(v[u].z), a[5]);
            a[6] = fmaf(w[u], bflo(v[u].w), a[6]); a[7] = fmaf(w[u], bfhi(v[u].w), a[7]);
        }
    }
    if (j < c) {
        int idx[8];
#pragma unroll
        for (int u = 0; u < 8; u++) { int e = j + u; idx[u] = csr[start + (e < c ? e : c - 1)]; }
        uint4 v[8]; float w[8];
#pragma unroll
        for (int u = 0; u < 8; u++) v[u] = base[(size_t)idx[u] * 16 + q];
#pragma unroll
        for (int u = 0; u < 8; u++) w[u] = dis[idx[u]];
#pragma unroll
        for (int u = 0; u < 8; u++) {
            if (j + u < c) {
                a[0] = fmaf(w[u], bflo(v[u].x), a[0]); a[1] = fmaf(w[u], bfhi(v[u].x), a[1]);
                a[2] = fmaf(w[u], bflo(v[u].y), a[2]); a[3] = fmaf(w[u], bfhi(v[u].y), a[3]);
                a[4] = fmaf(w[u], bflo(v[u].z), a[4]); a[5] = fmaf(w[u], bfhi(v[u].z), a[5]);
                a[6] = fmaf(w[u], bflo(v[u].w), a[6]); a[7] = fmaf(w[u], bfhi(v[u].w), a[7]);
            }
        }
    }

    const float4* bp = (const float4*)bias;
    float4 b0 = bp[q * 2], b1 = bp[q * 2 + 1];
    uint4 o;
    {
        float ox = fmaxf(fmaf(d, a[0], b0.x), 0.f), oy = fmaxf(fmaf(d, a[1], b0.y), 0.f);
        o.x = ((unsigned)f2bf(oy) << 16) | (unsigned)f2bf(ox);
        ox = fmaxf(fmaf(d, a[2], b0.z), 0.f); oy = fmaxf(fmaf(d, a[3], b0.w), 0.f);
        o.y = ((unsigned)f2bf(oy) << 16) | (unsigned)f2bf(ox);
        ox = fmaxf(fmaf(d, a[4], b1.x), 0.f); oy = fmaxf(fmaf(d, a[5], b1.y), 0.f);
        o.z = ((unsigned)f2bf(oy) << 16) | (unsigned)f2bf(ox);
        ox = fmaxf(fmaf(d, a[6], b1.z), 0.f); oy = fmaxf(fmaf(d, a[7], b1.w), 0.f);
        o.w = ((unsigned)f2bf(oy) << 16) | (unsigned)f2bf(ox);
    }
    ((uint4*)out)[(size_t)n * 16 + q] = o;
}

// ---------------- MFMA GEMM layer 2: out = bf16((A @ W2) * dis), A bf16 ----------
__launch_bounds__(256, 2)
__global__ void k_gemm2(const unsigned short* __restrict__ Av,
                        const unsigned short* __restrict__ WT,
                        const float* __restrict__ dis,
                        unsigned short* __restrict__ out) {
    int tid = threadIdx.x;
    int wave = tid >> 6, lane = tid & 63;
    int quad = lane >> 4, l16 = lane & 15;

    int rbase = blockIdx.x * 128 + wave * 32;

    bf16x8 af[2][4];
#pragma unroll
    for (int s = 0; s < 2; s++) {
        int row = rbase + s * 16 + l16;
        if (row >= NN) row = NN - 1;
        const unsigned short* arow = Av + (size_t)row * CH + quad * 8;
#pragma unroll
        for (int ks = 0; ks < 4; ks++) af[s][ks] = *(const bf16x8*)(arow + ks * 32);
    }

    f32x4 acc[2][8];
#pragma unroll
    for (int s = 0; s < 2; s++)
#pragma unroll
        for (int t = 0; t < 8; t++) acc[s][t] = (f32x4){0.f, 0.f, 0.f, 0.f};

#pragma unroll
    for (int t = 0; t < 8; t++) {
        const unsigned short* wcol = WT + (size_t)(t * 16 + l16) * CH + quad * 8;
        bf16x8 b0 = *(const bf16x8*)(wcol);
        bf16x8 b1 = *(const bf16x8*)(wcol + 32);
        bf16x8 b2 = *(const bf16x8*)(wcol + 64);
        bf16x8 b3 = *(const bf16x8*)(wcol + 96);
#pragma unroll
        for (int s = 0; s < 2; s++) {
            acc[s][t] = __builtin_amdgcn_mfma_f32_16x16x32_bf16(af[s][0], b0, acc[s][t], 0, 0, 0);
            acc[s][t] = __builtin_amdgcn_mfma_f32_16x16x32_bf16(af[s][1], b1, acc[s][t], 0, 0, 0);
            acc[s][t] = __builtin_amdgcn_mfma_f32_16x16x32_bf16(af[s][2], b2, acc[s][t], 0, 0, 0);
            acc[s][t] = __builtin_amdgcn_mfma_f32_16x16x32_bf16(af[s][3], b3, acc[s][t], 0, 0, 0);
        }
    }

    // D layout per 16x16 tile: row = quad*4 + r, col = l16
#pragma unroll
    for (int s = 0; s < 2; s++) {
#pragma unroll
        for (int r = 0; r < 4; r++) {
            int orow = rbase + s * 16 + quad * 4 + r;
            if (orow < NN) {
                float d = dis[orow];
#pragma unroll
                for (int t = 0; t < 8; t++) {
                    out[(size_t)orow * CH + t * 16 + l16] = f2bf(acc[s][t][r] * d);
                }
            }
        }
    }
}

// ---------------- agg layer 2: proven kernel, verbatim (59.7 us floor) ----------
__global__ __launch_bounds__(256) void k_agg(const unsigned short* __restrict__ ht, const int* __restrict__ rowst,
                      const int* __restrict__ degi, const int* __restrict__ csr,
                      const float* __restrict__ dis, const float* __restrict__ bias,
                      unsigned short* __restrict__ out) {
    int t = threadIdx.x;
    int grp = t >> 4;
    int q = t & 15;
    int n = blockIdx.x * 16 + grp;
    const uint4* base = (const uint4*)ht;

    uint4 sv = base[(size_t)n * 16 + q];
    float a[8];
    a[0] = bflo(sv.x); a[1] = bfhi(sv.x);
    a[2] = bflo(sv.y); a[3] = bfhi(sv.y);
    a[4] = bflo(sv.z); a[5] = bfhi(sv.z);
    a[6] = bflo(sv.w); a[7] = bfhi(sv.w);

    int start = rowst[n];
    int c = degi[n];
    int nb = c & ~7;
    int j = 0;
    for (; j < nb; j += 8) {
        int idx[8];
#pragma unroll
        for (int u = 0; u < 8; u++) idx[u] = csr[start + j + u];
        uint4 v[8];
#pragma unroll
        for (int u = 0; u < 8; u++) v[u] = base[(size_t)idx[u] * 16 + q];
#pragma unroll
        for (int u = 0; u < 8; u++) {
            a[0] += bflo(v[u].x); a[1] += bfhi(v[u].x);
            a[2] += bflo(v[u].y); a[3] += bfhi(v[u].y);
            a[4] += bflo(v[u].z); a[5] += bfhi(v[u].z);
            a[6] += bflo(v[u].w); a[7] += bfhi(v[u].w);
        }
    }
    if (j < c) {
        int idx[8];
#pragma unroll
        for (int u = 0; u < 8; u++) { int e = j + u; idx[u] = csr[start + (e < c ? e : c - 1)]; }
        uint4 v[8];
#pragma unroll
        for (int u = 0; u < 8; u++) v[u] = base[(size_t)idx[u] * 16 + q];
#pragma unroll
        for (int u = 0; u < 8; u++) {
            if (j + u < c) {
                a[0] += bflo(v[u].x); a[1] += bfhi(v[u].x);
                a[2] += bflo(v[u].y); a[3] += bfhi(v[u].y);
                a[4] += bflo(v[u].z); a[5] += bfhi(v[u].z);
                a[6] += bflo(v[u].w); a[7] += bfhi(v[u].w);
            }
        }
    }

    float d = dis[n];
    const float4* bp = (const float4*)bias;
    float4 b0 = bp[q * 2], b1 = bp[q * 2 + 1];
    uint4 o;
    {
        float ox = fmaxf(fmaf(d, a[0], b0.x), 0.f), oy = fmaxf(fmaf(d, a[1], b0.y), 0.f);
        o.x = ((unsigned)f2bf(oy) << 16) | (unsigned)f2bf(ox);
        ox = fmaxf(fmaf(d, a[2], b0.z), 0.f); oy = fmaxf(fmaf(d, a[3], b0.w), 0.f);
        o.y = ((unsigned)f2bf(oy) << 16) | (unsigned)f2bf(ox);
        ox = fmaxf(fmaf(d, a[4], b1.x), 0.f); oy = fmaxf(fmaf(d, a[5], b1.y), 0.f);
        o.z = ((unsigned)f2bf(oy) << 16) | (unsigned)f2bf(ox);
        ox = fmaxf(fmaf(d, a[6], b1.z), 0.f); oy = fmaxf(fmaf(d, a[7], b1.w), 0.f);
        o.w = ((unsigned)f2bf(oy) << 16) | (unsigned)f2bf(ox);
    }
    ((uint4*)out)[(size_t)n * 16 + q] = o;
}

// ---------------- mean pool: 8 splits/graph, LDS reduce, few atomics ----------------
__global__ __launch_bounds__(512) void k_pool2(const unsigned short* __restrict__ h,
                                               const int* __restrict__ gptr,
                                               float* __restrict__ pooled) {
    int g = blockIdx.x >> 3;       // graph
    int s = blockIdx.x & 7;        // split
    int gs = gptr[g], ge = gptr[g + 1];
    int len = ge - gs;
    int i0 = gs + (int)(((long long)len * s) >> 3);
    int i1 = gs + (int)(((long long)len * (s + 1)) >> 3);
    int t = threadIdx.x;
    int pr = t & 63;               // channel pair 0..63
    int ro = t >> 6;               // row group 0..7
    const unsigned* base = (const unsigned*)h;
    float s0 = 0.f, s1 = 0.f;
    for (int n = i0 + ro; n < i1; n += 8) {
        unsigned v = base[(size_t)n * 64 + pr];
        s0 += bflo(v); s1 += bfhi(v);
    }
    __shared__ float red[2][8][64];
    red[0][ro][pr] = s0; red[1][ro][pr] = s1;
    __syncthreads();
    for (int off = 4; off >= 1; off >>= 1) {
        if (ro < off) {
            red[0][ro][pr] += red[0][ro + off][pr];
            red[1][ro][pr] += red[1][ro + off][pr];
        }
        __syncthreads();
    }
    if (ro == 0) {
        atomicAdd(&pooled[g * CH + pr * 2],     red[0][0][pr]);
        atomicAdd(&pooled[g * CH + pr * 2 + 1], red[1][0][pr]);
    }
}

// ---------------- final FC: out = (pooled/cnt) @ Wfc + bfc ----------------
__global__ void k_final(const float* __restrict__ pooled, const int* __restrict__ gptr,
                        const float* __restrict__ Wfc, const float* __restrict__ bfc,
                        float* __restrict__ out) {
    int idx = blockIdx.x * 256 + threadIdx.x;
    if (idx >= NG * OUTC) return;
    int g = idx >> 4, o = idx & 15;
    float c = (float)(gptr[g + 1] - gptr[g]);
    float inv = 1.0f / fmaxf(c, 1.0f);
    float s = 0.f;
    for (int k = 0; k < CH; k++) s += pooled[g * CH + k] * Wfc[k * OUTC + o];
    out[idx] = fmaf(s, inv, bfc[o]);
}

extern "C" void kernel_launch(void* const* d_in, const int* in_sizes, int n_in,
                              void* d_out, int out_size, void* d_ws, size_t ws_size,
                              hipStream_t stream) {
    (void)in_sizes; (void)n_in; (void)out_size; (void)ws_size;
    const float* x   = (const float*)d_in[0];
    const float* W1  = (const float*)d_in[1];
    const float* b1  = (const float*)d_in[2];
    const float* W2  = (const float*)d_in[3];
    const float* b2  = (const float*)d_in[4];
    const float* Wfc = (const float*)d_in[5];
    const float* bfc = (const float*)d_in[6];
    const int* ei    = (const int*)d_in[7];
    const int* batch = (const int*)d_in[8];
    const int* esrc = ei;
    const int* edst = ei + NE;
    float* out = (float*)d_out;

    char* w = (char*)d_ws;
    unsigned short* bufA = (unsigned short*)w; w += (size_t)NN * CH * 2;
    unsigned short* bufB = (unsigned short*)w; w += (size_t)NN * CH * 2;
    unsigned short* wt2  = (unsigned short*)w; w += (size_t)CH * CH * 2;
    unsigned* ebuf = (unsigned*)w; w += (size_t)NE * 4;
    int* csr    = (int*)w;    w += (size_t)NE * 4;
    int* degi   = (int*)w;    w += (size_t)NN * 4;
    int* rowst  = (int*)w;    w += (size_t)NN * 4;
    float* dis  = (float*)w;  w += (size_t)NN * 4;
    int* bcnt   = (int*)w;    w += NCB * 4;
    int* ebase  = (int*)w;    w += (NCB + 1) * 4;
    int* gfill  = (int*)w;    w += NCB * 4;
    int* gptr   = (int*)w;    w += (NG + 1) * 4;
    float* pooled = (float*)w; w += (size_t)NG * CH * 4;

    const int gemmBlocks = (NN + 127) / 128;         // 782
    const int aggBlocks  = NN / 16;                  // 6250
    const int passABlocks = (NE + CHK - 1) / CHK;    // 391

    hipMemsetAsync(bcnt, 0, NCB * sizeof(int), stream);

    // fused: hist (global-atomic bcnt) | prep
    k_fused0<<<HISTB + PREPB, 256, 0, stream>>>(edst, bcnt, W2, wt2, batch, gptr, gfill, pooled);
    // counting-sort pass A (391 blocks, folded bucket-base scan; block 0 -> ebase)
    k_passA<<<passABlocks, 512, 0, stream>>>(esrc, edst, bcnt, gfill, ebuf, ebase);
    // fused: passB (391 blocks) | gemm1 (782 blocks, unscaled output)
    k_fusedB<<<NCB + gemmBlocks, 256, 0, stream>>>(ebuf, ebase, degi, rowst, dis, csr, x, W1, bufA);

    // layer 1 aggregation (dis-weighted gather over unscaled bufA)
    k_agg_w<<<aggBlocks, 256, 0, stream>>>(bufA, rowst, degi, csr, dis, b1, bufB);
    // layer 2 (bf16 input, dis-scaled output)
    k_gemm2<<<gemmBlocks, 256, 0, stream>>>(bufB, wt2, dis, bufA);
    k_agg<<<aggBlocks, 256, 0, stream>>>(bufA, rowst, degi, csr, dis, b2, bufB);

    k_pool2<<<NG * PS, 512, 0, stream>>>(bufB, gptr, pooled);
    k_final<<<(NG * OUTC + 255) / 256, 256, 0, stream>>>(pooled, gptr, Wfc, bfc, out);
}